// Round 4
// baseline (291.262 us; speedup 1.0000x reference)
//
#include <hip/hip_runtime.h>

// PerformerAttention: B=4 H=16 S=4096 D=64, fp32.
//   q = relu(Q)+eps; k = (relu(K)+eps)*mask
//   kv[bh][d][e] = sum_s k[s][d]*v[s][e];  ksum[bh][d] = sum_s k[s][d]
//   out[s][e] = (sum_d q[s][d]*kv[d][e]) / (sum_d q[s][d]*ksum[d])
//
// R8: R7 was correct (WAR lgkm guard works) and the depth-3 pipeline raised
// HBM 1.37->1.85 TB/s, but it re-triggered the R5 spill signature (VGPR 128 /
// SGPR 112, +73 MB scratch writes): per-round UNROLLED 64-bit address
// recomputation created ~8 hoisted wave-uniform SGPR base pairs across the
// asm-fenced regions, blowing the ~102-SGPR budget -> SGPR spill -> scratch.
// Fix: running per-lane VGPR pointers kp/vp advanced += 16*kD per issuing
// round; no other change. Pipeline (unchanged from R7):
//   * K and V via global_load_lds into wave-private ring-4 of 4-row tiles
//     (2 KB/slot, 8 KB/wave); slot indices compile-time (unroll x4).
//   * round t issues t+3; s_waitcnt vmcnt(6)/round keeps 6 VMEM in flight.
//   * s_waitcnt lgkmcnt(0) WAR guard before each issue (slot reuse).
//   * mask preloaded to LDS behind a vmcnt-draining __syncthreads().
//   * K preprocessing (relu*m + eps*m) at LDS-read time; ksum per-lane col.
// Fallback if spill signature reappears: revert to R4 depth-1 + CH1=32.
// pa_reduce / pa_out / launcher unchanged (attribution).

namespace {
constexpr int kB = 4, kH = 16, kS = 4096, kD = 64;
constexpr int kBH = kB * kH;
constexpr float kEps = 0.001f;

constexpr int KVSZ = kD * kD;     // 4096 floats
constexpr int SEG  = KVSZ + kD;   // 4160 floats per partial segment (kv + ksum)
constexpr int F4PS = SEG / 4;     // 1040 float4 per segment
}

// async global->LDS, 16 B per lane; LDS dest = wave-uniform base + lane*16
__device__ __forceinline__ void async_cp16(const float* g, float* l) {
  __builtin_amdgcn_global_load_lds(
      (const __attribute__((address_space(1))) void*)g,
      (__attribute__((address_space(3))) void*)l, 16, 0, 0);
}

// ---------------- Pass 1: partial kv + ksum, one segment per BLOCK ---------
__global__ __launch_bounds__(256, 2)   // (256,4) caused a 64-VGPR spill disaster; do not re-add
void pa_kv_partial(const float* __restrict__ key, const float* __restrict__ value,
                   const float* __restrict__ mask, float* __restrict__ P, int ch1) {
  // 4 waves x ring-4 x (K 256f + V 256f) = 8192 floats; combine reuses [0..4096)
  __shared__ float smemU[8192];
  __shared__ float msk[512];         // block's mask slice (keeps loop free of other VMEM)
  __shared__ float ksm[256];         // per-wave ksum staging [wave][64]

  const int tid  = threadIdx.x;
  const int wid  = tid >> 6;
  const int lane = tid & 63;

  const int bh    = blockIdx.x / ch1;
  const int chunk = blockIdx.x - bh * ch1;
  const int b     = bh >> 4;                 // kH = 16
  const int rows  = kS / ch1;
  const int s0    = chunk * rows;
  const int rounds = rows >> 4;              // 16-row rounds (4 rows/wave), mult of 4

  const float* kg = key   + (size_t)bh * kS * kD;
  const float* vg = value + (size_t)bh * kS * kD;
  const float* mb = mask  + (size_t)b * kS;

  for (int i = tid; i < rows; i += 256) msk[i] = mb[s0 + i];
  __syncthreads();                           // drains vmcnt -> clean counter base

  float* const ring = smemU + wid * 2048;    // wave-private 8 KB ring
#define RK(Pp) (ring + (Pp) * 512)           // K slot: 4x64 floats, linear
#define RV(Pp) (ring + (Pp) * 512 + 256)     // V slot: 4x64 floats, linear

  const int ti = lane >> 3;                  // 0..7 (d rows 8*ti..)
  const int tj = lane & 7;                   // 0..7 (e cols 8*tj..)
  const int rw = wid * 4;                    // wave's row offset within a round

  float acc[8][8];
#pragma unroll
  for (int i = 0; i < 8; ++i)
#pragma unroll
    for (int j = 0; j < 8; ++j) acc[i][j] = 0.f;
  float ksacc = 0.f;                         // lane owns column d = lane

  // Running per-lane load pointers (VGPR pairs) — the ONLY global addresses
  // in the whole loop. Advanced by one 16-row round (16*kD floats) per issue.
  const float* kp = kg + (size_t)(s0 + rw) * kD + lane * 4;
  const float* vp = vg + (size_t)(s0 + rw) * kD + lane * 4;

  // ---- prologue: issue rounds 0,1,2 into slots 0,1,2 (6 VMEM in flight) ----
  async_cp16(kp, RK(0));
  async_cp16(vp, RV(0));
  kp += 16 * kD; vp += 16 * kD;
  asm volatile("" ::: "memory");
  async_cp16(kp, RK(1));
  async_cp16(vp, RV(1));
  kp += 16 * kD; vp += 16 * kD;
  asm volatile("" ::: "memory");
  async_cp16(kp, RK(2));
  async_cp16(vp, RV(2));
  kp += 16 * kD; vp += 16 * kD;              // -> round 3 (next issue)
  asm volatile("" ::: "memory");

  // One round:
  //   [issue] lgkmcnt(0)  -- WAR guard: slot (P+3)&3 == (P-1)&3 was consumed
  //                          last round; its ds_reads must be register-
  //                          captured before the overwriting load is enqueued
  //                          (also blocks compiler hoist of the cp16 above
  //                          those reads — the builtin's LDS-write side is
  //                          not reliably modeled).
  //           issue round r+3 via running pointers (2 VMEM), advance.
  //   vmcnt(WAITN)        -- steady state: 8 outstanding -> 6; round r landed.
  //   consume slot P (relu/eps/mask at read time, 64x8x8 FMA block).
#define PA_RND(Pp, RR, DO_ISSUE, WAITN)                                       \
  {                                                                           \
    if (DO_ISSUE) {                                                           \
      asm volatile("s_waitcnt lgkmcnt(0)" ::: "memory");                      \
      async_cp16(kp, RK(((Pp) + 3) & 3));                                     \
      async_cp16(vp, RV(((Pp) + 3) & 3));                                     \
      kp += 16 * kD; vp += 16 * kD;                                           \
    }                                                                         \
    asm volatile("s_waitcnt vmcnt(" #WAITN ")" ::: "memory");                 \
    const float* Ks = RK(Pp);                                                 \
    const float* Vs = RV(Pp);                                                 \
    const int rb = (RR) * 16 + rw;                                            \
    _Pragma("unroll")                                                         \
    for (int ss = 0; ss < 4; ++ss) {                                          \
      const float m  = msk[rb + ss];                                          \
      const float em = kEps * m;                                              \
      ksacc += fmaf(fmaxf(Ks[ss * 64 + lane], 0.f), m, em);                   \
      const float4 kf0 = *(const float4*)&Ks[ss * 64 + 8 * ti];               \
      const float4 kf1 = *(const float4*)&Ks[ss * 64 + 8 * ti + 4];           \
      const float4 vf0 = *(const float4*)&Vs[ss * 64 + 8 * tj];               \
      const float4 vf1 = *(const float4*)&Vs[ss * 64 + 8 * tj + 4];           \
      float ka[8];                                                            \
      ka[0] = fmaf(fmaxf(kf0.x, 0.f), m, em);                                 \
      ka[1] = fmaf(fmaxf(kf0.y, 0.f), m, em);                                 \
      ka[2] = fmaf(fmaxf(kf0.z, 0.f), m, em);                                 \
      ka[3] = fmaf(fmaxf(kf0.w, 0.f), m, em);                                 \
      ka[4] = fmaf(fmaxf(kf1.x, 0.f), m, em);                                 \
      ka[5] = fmaf(fmaxf(kf1.y, 0.f), m, em);                                 \
      ka[6] = fmaf(fmaxf(kf1.z, 0.f), m, em);                                 \
      ka[7] = fmaf(fmaxf(kf1.w, 0.f), m, em);                                 \
      const float va_[8] = {vf0.x, vf0.y, vf0.z, vf0.w,                       \
                            vf1.x, vf1.y, vf1.z, vf1.w};                      \
      _Pragma("unroll")                                                       \
      for (int i = 0; i < 8; ++i)                                             \
        _Pragma("unroll")                                                     \
        for (int j = 0; j < 8; ++j)                                           \
          acc[i][j] = fmaf(ka[i], va_[j], acc[i][j]);                         \
    }                                                                         \
  }

  // main: every round r <= rounds-5 issues r+3 (slots compile-time: t mult of 4)
  int t = 0;
  for (; t < rounds - 7; t += 4) {
    PA_RND(0, t + 0, true, 6)
    PA_RND(1, t + 1, true, 6)
    PA_RND(2, t + 2, true, 6)
    PA_RND(3, t + 3, true, 6)
  }
  // tail: t == rounds-4; first tail round issues rounds-1, then drain 4/2/0
  PA_RND(0, t + 0, true, 6)
  PA_RND(1, t + 1, false, 4)
  PA_RND(2, t + 2, false, 2)
  PA_RND(3, t + 3, false, 0)
#undef PA_RND
#undef RK
#undef RV

  // per-wave ksum: lane owns column d = lane (no shuffles needed)
  ksm[wid * 64 + lane] = ksacc;

  // block combine: wave w adds its 8x8 acc into smemU[0..4096) (permuted
  // layout: f4 slot j*64+lane = kv[8*(lane>>3)+(j>>1)][8*(lane&7)+4*(j&1)..])
#pragma unroll
  for (int w = 0; w < 4; ++w) {
    __syncthreads();
    if (wid == w) {
#pragma unroll
      for (int i = 0; i < 8; ++i)
#pragma unroll
        for (int jj = 0; jj < 2; ++jj) {
          const int j = i * 2 + jj;
          float4 o = make_float4(acc[i][jj * 4 + 0], acc[i][jj * 4 + 1],
                                 acc[i][jj * 4 + 2], acc[i][jj * 4 + 3]);
          float* p = &smemU[(size_t)(j * 64 + lane) * 4];
          if (w != 0) {
            const float4 prev = *(const float4*)p;
            o.x += prev.x; o.y += prev.y; o.z += prev.z; o.w += prev.w;
          }
          *(float4*)p = o;
        }
    }
  }
  __syncthreads();

  // cooperative coalesced store of the single block segment
  float* Pd = P + (size_t)blockIdx.x * SEG;
#pragma unroll
  for (int i = 0; i < 4; ++i) {
    const int idx = tid + 256 * i;
    *(float4*)&Pd[(size_t)idx * 4] = *(const float4*)&smemU[(size_t)idx * 4];
  }
  if (tid < kD)
    Pd[KVSZ + tid] = ksm[tid] + ksm[64 + tid] + ksm[128 + tid] + ksm[192 + tid];
}

// ---------------- Reduce: sum block partials, un-permute kv ----------------
__global__ __launch_bounds__(256)
void pa_reduce(const float* __restrict__ P, float* __restrict__ R, int nseg) {
  const int gid = blockIdx.x * 256 + threadIdx.x;
  if (gid >= kBH * F4PS) return;
  const int bh  = gid / F4PS;
  const int pos = gid - bh * F4PS;

  const float* base = P + (size_t)bh * nseg * SEG + (size_t)pos * 4;
  float ax = 0.f, ay = 0.f, az = 0.f, aw = 0.f;
  for (int c = 0; c < nseg; ++c) {
    const float4 t = *(const float4*)(base + (size_t)c * SEG);
    ax += t.x; ay += t.y; az += t.z; aw += t.w;
  }

  int dpos;
  if (pos < KVSZ / 4) {          // un-permute to natural [d][e]
    const int j  = pos >> 6, ln = pos & 63;
    const int d  = 8 * (ln >> 3) + (j >> 1);
    const int e4 = 2 * (ln & 7) + (j & 1);
    dpos = d * 16 + e4;
  } else {
    dpos = pos;                  // ksum already natural
  }
  *(float4*)&R[(size_t)bh * SEG + (size_t)dpos * 4] = make_float4(ax, ay, az, aw);
}

// ---------------- Pass 2: out = (q . kv) / (q . ksum) ----------------------
__global__ __launch_bounds__(256)
void pa_out(const float* __restrict__ query, const float* __restrict__ R,
            float* __restrict__ out) {
  __shared__ float ost[64 * 68];   // 64-row output staging, pad 68 (17 KiB)

  const int tid    = threadIdx.x;
  const int bh     = blockIdx.x >> 4;
  const int rowblk = blockIdx.x & 15;
  const int s      = rowblk * 256 + tid;

  const float* qrow = query + ((size_t)bh * kS + s) * kD;
  const float* Rb   = R + (size_t)bh * SEG;   // wave-uniform -> scalar loads

  float4 acc[16];
#pragma unroll
  for (int e = 0; e < 16; ++e) acc[e] = make_float4(0.f, 0.f, 0.f, 0.f);
  float den = 0.f;

#pragma unroll 4
  for (int d4 = 0; d4 < 16; ++d4) {
    const float4 qv = *(const float4*)(qrow + 4 * d4);
    const float qd[4] = {fmaxf(qv.x, 0.f) + kEps, fmaxf(qv.y, 0.f) + kEps,
                         fmaxf(qv.z, 0.f) + kEps, fmaxf(qv.w, 0.f) + kEps};
#pragma unroll
    for (int dd = 0; dd < 4; ++dd) {
      const int d = 4 * d4 + dd;
      den = fmaf(qd[dd], Rb[KVSZ + d], den);
      const float* kvr = Rb + d * 64;          // uniform row -> SGPR broadcast
#pragma unroll
      for (int e = 0; e < 16; ++e) {
        acc[e].x = fmaf(qd[dd], kvr[4 * e + 0], acc[e].x);
        acc[e].y = fmaf(qd[dd], kvr[4 * e + 1], acc[e].y);
        acc[e].z = fmaf(qd[dd], kvr[4 * e + 2], acc[e].z);
        acc[e].w = fmaf(qd[dd], kvr[4 * e + 3], acc[e].w);
      }
    }
  }

  const float inv = 1.0f / den;
#pragma unroll
  for (int e = 0; e < 16; ++e) {
    acc[e].x *= inv; acc[e].y *= inv; acc[e].z *= inv; acc[e].w *= inv;
  }

  // staged coalesced store: batch bb covers 64 rows written by wave bb
  float* ob = out + ((size_t)bh * kS + (size_t)rowblk * 256) * kD;
  const int wid = tid >> 6, l = tid & 63;
  for (int bb = 0; bb < 4; ++bb) {
    if (wid == bb) {
#pragma unroll
      for (int e = 0; e < 16; ++e) *(float4*)&ost[l * 68 + 4 * e] = acc[e];
    }
    __syncthreads();
#pragma unroll
    for (int jj = 0; jj < 4; ++jj) {
      const int g = tid + 256 * jj;
      const int r = g >> 4, c = g & 15;
      *(float4*)&ob[(size_t)(bb * 64 + r) * kD + 4 * c] =
          *(const float4*)&ost[r * 68 + 4 * c];
    }
    __syncthreads();
  }
}

extern "C" void kernel_launch(void* const* d_in, const int* in_sizes, int n_in,
                              void* d_out, int out_size, void* d_ws, size_t ws_size,
                              hipStream_t stream) {
  const float* query = (const float*)d_in[0];
  const float* key   = (const float*)d_in[1];
  const float* value = (const float*)d_in[2];
  const float* mask  = (const float*)d_in[3];
  float* outp = (float*)d_out;

  // CH1 = S-chunks per bh; ONE segment per block. Pick largest that fits ws.
  auto need = [](int ch1) -> size_t {
    return (size_t)(kBH * ch1 + kBH) * SEG * sizeof(float);
  };
  int CH1 = 8;                                  // 9.2 MB, known-safe floor
  if (ws_size >= need(16)) CH1 = 16;            // 18.1 MB, 1024 blocks (4/CU)

  float* P = (float*)d_ws;                      // kBH*CH1 segments
  float* R = P + (size_t)kBH * CH1 * SEG;       // kBH segments (natural layout)

  hipLaunchKernelGGL(pa_kv_partial, dim3(kBH * CH1), dim3(256), 0, stream,
                     key, value, mask, P, CH1);
  hipLaunchKernelGGL(pa_reduce, dim3((kBH * F4PS + 255) / 256), dim3(256), 0, stream,
                     P, R, CH1);
  hipLaunchKernelGGL(pa_out, dim3(kBH * 16), dim3(256), 0, stream,
                     query, R, outp);
}

// Round 5
// 257.469 us; speedup vs baseline: 1.1313x; 1.1313x over previous
//
#include <hip/hip_runtime.h>

// PerformerAttention: B=4 H=16 S=4096 D=64, fp32.
//   q = relu(Q)+eps; k = (relu(K)+eps)*mask
//   kv[bh][d][e] = sum_s k[s][d]*v[s][e];  ksum[bh][d] = sum_s k[s][d]
//   out[s][e] = (sum_d q[s][d]*kv[d][e]) / (sum_d q[s][d]*ksum[d])
//
// R9: abandon the global_load_lds + inline-asm pipeline — 3 builds (R5/R7/R8)
// all hit the identical VGPR128/SGPR112 spill signature (+60..85 MB scratch).
// Back to the clean R4 structure (112/32, 60us), with the actual R4 stall
// fixed IN PLAIN C++: R4 issued loads kq,vq,m and consumed m (the NEWEST
// load) FIRST -> compiler's auto-wait = vmcnt(0) full drain each round, so
// the prefetch gave no cross-round overlap. Changes, nothing else:
//   1. mask preloaded to LDS (no per-round mask global load).
//   2. depth-2 register pipeline: two static reg sets A/B; a round consumes
//      set X (kq first, then vq - strict issue order so compiler emits
//      counted vmcnt(6)/vmcnt(4)), then re-issues X <- tile t+2. Static
//      parity via unroll-2. No asm, no builtins - compiler manages waits.
//   3. __launch_bounds__(256,1): +32 staging VGPRs must not hit a 128 cap
//      (that cap is what spilled (256,4) long ago). Expect ~140-160 VGPR,
//      3 waves/SIMD.
// Wave-private LDS tile still needs no barrier: same-wave DS ops are in
// order, so next round's ds_write queues after this round's ds_reads.
// pa_reduce / pa_out / launcher byte-identical to R4 (attribution).

namespace {
constexpr int kB = 4, kH = 16, kS = 4096, kD = 64;
constexpr int kBH = kB * kH;
constexpr float kEps = 0.001f;

constexpr int KVSZ = kD * kD;     // 4096 floats
constexpr int SEG  = KVSZ + kD;   // 4160 floats per partial segment (kv + ksum)
constexpr int F4PS = SEG / 4;     // 1040 float4 per segment
}

// ---------------- Pass 1: partial kv + ksum, one segment per BLOCK ---------
__global__ __launch_bounds__(256, 1)
void pa_kv_partial(const float* __restrict__ key, const float* __restrict__ value,
                   const float* __restrict__ mask, float* __restrict__ P, int ch1) {
  __shared__ float smem[4096];   // 4 waves x (ks 512 + vs 512); reused for combine
  __shared__ float msk[512];     // block's mask slice (LDS, not per-round VMEM)
  __shared__ float ksm[256];     // per-wave ksum staging

  const int tid  = threadIdx.x;
  const int wid  = tid >> 6;
  const int lane = tid & 63;

  const int bh    = blockIdx.x / ch1;
  const int chunk = blockIdx.x - bh * ch1;
  const int b     = bh >> 4;                 // kH = 16
  const int rows  = kS / ch1;
  const int s0    = chunk * rows;
  const int tiles = rows >> 5;               // 8-row tiles, strided by 4 waves

  const float* kb = key   + (size_t)bh * kS * kD;
  const float* vb = value + (size_t)bh * kS * kD;
  const float* mb = mask  + (size_t)b * kS;

  for (int i = tid; i < rows; i += 256) msk[i] = mb[s0 + i];
  __syncthreads();

  float* ksT = smem + wid * 1024;            // 8 x 64 (wave-private)
  float* vsT = smem + wid * 1024 + 512;      // 8 x 64

  const int lrow = lane >> 4;                // 0..3   (load map)
  const int lcol = (lane & 15) << 2;         // 0..60
  const int ti   = lane >> 3;                // 0..7   (compute map: d rows 8*ti..)
  const int tj   = lane & 7;                 // 0..7   (e cols 8*tj..)

  float acc[8][8];
#pragma unroll
  for (int i = 0; i < 8; ++i)
#pragma unroll
    for (int j = 0; j < 8; ++j) acc[i][j] = 0.f;
  float4 ksacc = make_float4(0.f, 0.f, 0.f, 0.f);

  // Per-lane element offsets within a tile (tile base row = s0 + t*32 + wid*8)
  const size_t eoff0 = (size_t)(lrow)     * kD + lcol;   // rows 0..3 of tile
  const size_t eoff1 = (size_t)(lrow + 4) * kD + lcol;   // rows 4..7 of tile
  const int    trow  = wid * 8;                          // wave row in 32-row group

  // ---- prologue: issue tile 0 -> set A, tile 1 -> set B (issue order:
  //      kq0,kq1,vq0,vq1 per set; consumed in the same order) ----
  const float* kt0p = kb + (size_t)(s0 + trow) * kD;
  const float* vt0p = vb + (size_t)(s0 + trow) * kD;
  float4 kqA0 = *(const float4*)(kt0p + eoff0);
  float4 kqA1 = *(const float4*)(kt0p + eoff1);
  float4 vqA0 = *(const float4*)(vt0p + eoff0);
  float4 vqA1 = *(const float4*)(vt0p + eoff1);
  float4 kqB0 = *(const float4*)(kt0p + 32 * kD + eoff0);
  float4 kqB1 = *(const float4*)(kt0p + 32 * kD + eoff1);
  float4 vqB0 = *(const float4*)(vt0p + 32 * kD + eoff0);
  float4 vqB1 = *(const float4*)(vt0p + 32 * kD + eoff1);

  // One round, set X holds tile TT:
  //   1. kt = (relu(kqX)+eps)*m   (m from LDS; kqX is the OLDEST outstanding
  //      pair -> compiler waits a counted vmcnt, newer loads stay in flight)
  //   2. ksacc += ...
  //   3. ds_write ksT<-kt, vsT<-vqX  (vqX next-oldest -> counted vmcnt)
  //   4. re-issue X <- tile TT+2 (X regs dead after step 3)
  //   5. FMA block over ksT/vsT (same-wave DS in-order: no barrier needed)
#define PA_RND(KQ0, KQ1, VQ0, VQ1, TT)                                        \
  {                                                                           \
    const int rb = (TT) * 32 + trow;                                          \
    const float m0 = msk[rb + lrow];                                          \
    const float m1 = msk[rb + 4 + lrow];                                      \
    float4 kt0, kt1;                                                          \
    kt0.x = (fmaxf(KQ0.x, 0.f) + kEps) * m0;                                  \
    kt0.y = (fmaxf(KQ0.y, 0.f) + kEps) * m0;                                  \
    kt0.z = (fmaxf(KQ0.z, 0.f) + kEps) * m0;                                  \
    kt0.w = (fmaxf(KQ0.w, 0.f) + kEps) * m0;                                  \
    kt1.x = (fmaxf(KQ1.x, 0.f) + kEps) * m1;                                  \
    kt1.y = (fmaxf(KQ1.y, 0.f) + kEps) * m1;                                  \
    kt1.z = (fmaxf(KQ1.z, 0.f) + kEps) * m1;                                  \
    kt1.w = (fmaxf(KQ1.w, 0.f) + kEps) * m1;                                  \
    ksacc.x += kt0.x + kt1.x;                                                 \
    ksacc.y += kt0.y + kt1.y;                                                 \
    ksacc.z += kt0.z + kt1.z;                                                 \
    ksacc.w += kt0.w + kt1.w;                                                 \
    *(float4*)&ksT[lrow * 64 + lcol]       = kt0;                             \
    *(float4*)&ksT[(lrow + 4) * 64 + lcol] = kt1;                             \
    *(float4*)&vsT[lrow * 64 + lcol]       = VQ0;                             \
    *(float4*)&vsT[(lrow + 4) * 64 + lcol] = VQ1;                             \
    if ((TT) + 2 < tiles) {                                                   \
      const float* kn = kb + (size_t)(s0 + ((TT) + 2) * 32 + trow) * kD;      \
      const float* vn = vb + (size_t)(s0 + ((TT) + 2) * 32 + trow) * kD;      \
      KQ0 = *(const float4*)(kn + eoff0);                                     \
      KQ1 = *(const float4*)(kn + eoff1);                                     \
      VQ0 = *(const float4*)(vn + eoff0);                                     \
      VQ1 = *(const float4*)(vn + eoff1);                                     \
    }                                                                         \
    _Pragma("unroll")                                                         \
    for (int ss = 0; ss < 8; ++ss) {                                          \
      const float4 kf0 = *(const float4*)&ksT[ss * 64 + 8 * ti];              \
      const float4 kf1 = *(const float4*)&ksT[ss * 64 + 8 * ti + 4];          \
      const float4 vf0 = *(const float4*)&vsT[ss * 64 + 8 * tj];              \
      const float4 vf1 = *(const float4*)&vsT[ss * 64 + 8 * tj + 4];          \
      const float ka[8] = {kf0.x, kf0.y, kf0.z, kf0.w,                        \
                           kf1.x, kf1.y, kf1.z, kf1.w};                       \
      const float va_[8] = {vf0.x, vf0.y, vf0.z, vf0.w,                       \
                            vf1.x, vf1.y, vf1.z, vf1.w};                      \
      _Pragma("unroll")                                                       \
      for (int i = 0; i < 8; ++i)                                             \
        _Pragma("unroll")                                                     \
        for (int j = 0; j < 8; ++j)                                           \
          acc[i][j] = fmaf(ka[i], va_[j], acc[i][j]);                         \
    }                                                                         \
  }

  for (int t = 0; t < tiles; t += 2) {       // tiles is even (8 @ CH1=16)
    PA_RND(kqA0, kqA1, vqA0, vqA1, t)
    PA_RND(kqB0, kqB1, vqB0, vqB1, t + 1)
  }
#undef PA_RND

  // per-wave ksum fold: lanes sharing (lane&15) hold disjoint row partials
  ksacc.x += __shfl_xor(ksacc.x, 16); ksacc.x += __shfl_xor(ksacc.x, 32);
  ksacc.y += __shfl_xor(ksacc.y, 16); ksacc.y += __shfl_xor(ksacc.y, 32);
  ksacc.z += __shfl_xor(ksacc.z, 16); ksacc.z += __shfl_xor(ksacc.z, 32);
  ksacc.w += __shfl_xor(ksacc.w, 16); ksacc.w += __shfl_xor(ksacc.w, 32);
  if (lane < 16) *(float4*)&ksm[wid * 64 + 4 * lane] = ksacc;

  // block combine: wave w adds its 8x8 acc into smem[4096] (permuted layout:
  // f4 slot j*64+lane = kv[8*(lane>>3)+(j>>1)][8*(lane&7)+4*(j&1)..])
#pragma unroll
  for (int w = 0; w < 4; ++w) {
    __syncthreads();
    if (wid == w) {
#pragma unroll
      for (int i = 0; i < 8; ++i)
#pragma unroll
        for (int jj = 0; jj < 2; ++jj) {
          const int j = i * 2 + jj;
          float4 o = make_float4(acc[i][jj * 4 + 0], acc[i][jj * 4 + 1],
                                 acc[i][jj * 4 + 2], acc[i][jj * 4 + 3]);
          float* p = &smem[(size_t)(j * 64 + lane) * 4];
          if (w != 0) {
            const float4 prev = *(const float4*)p;
            o.x += prev.x; o.y += prev.y; o.z += prev.z; o.w += prev.w;
          }
          *(float4*)p = o;
        }
    }
  }
  __syncthreads();

  // cooperative coalesced store of the single block segment
  float* Pd = P + (size_t)blockIdx.x * SEG;
#pragma unroll
  for (int i = 0; i < 4; ++i) {
    const int idx = tid + 256 * i;
    *(float4*)&Pd[(size_t)idx * 4] = *(const float4*)&smem[(size_t)idx * 4];
  }
  if (tid < kD)
    Pd[KVSZ + tid] = ksm[tid] + ksm[64 + tid] + ksm[128 + tid] + ksm[192 + tid];
}

// ---------------- Reduce: sum block partials, un-permute kv ----------------
__global__ __launch_bounds__(256)
void pa_reduce(const float* __restrict__ P, float* __restrict__ R, int nseg) {
  const int gid = blockIdx.x * 256 + threadIdx.x;
  if (gid >= kBH * F4PS) return;
  const int bh  = gid / F4PS;
  const int pos = gid - bh * F4PS;

  const float* base = P + (size_t)bh * nseg * SEG + (size_t)pos * 4;
  float ax = 0.f, ay = 0.f, az = 0.f, aw = 0.f;
  for (int c = 0; c < nseg; ++c) {
    const float4 t = *(const float4*)(base + (size_t)c * SEG);
    ax += t.x; ay += t.y; az += t.z; aw += t.w;
  }

  int dpos;
  if (pos < KVSZ / 4) {          // un-permute to natural [d][e]
    const int j  = pos >> 6, ln = pos & 63;
    const int d  = 8 * (ln >> 3) + (j >> 1);
    const int e4 = 2 * (ln & 7) + (j & 1);
    dpos = d * 16 + e4;
  } else {
    dpos = pos;                  // ksum already natural
  }
  *(float4*)&R[(size_t)bh * SEG + (size_t)dpos * 4] = make_float4(ax, ay, az, aw);
}

// ---------------- Pass 2: out = (q . kv) / (q . ksum) ----------------------
__global__ __launch_bounds__(256)
void pa_out(const float* __restrict__ query, const float* __restrict__ R,
            float* __restrict__ out) {
  __shared__ float ost[64 * 68];   // 64-row output staging, pad 68 (17 KiB)

  const int tid    = threadIdx.x;
  const int bh     = blockIdx.x >> 4;
  const int rowblk = blockIdx.x & 15;
  const int s      = rowblk * 256 + tid;

  const float* qrow = query + ((size_t)bh * kS + s) * kD;
  const float* Rb   = R + (size_t)bh * SEG;   // wave-uniform -> scalar loads

  float4 acc[16];
#pragma unroll
  for (int e = 0; e < 16; ++e) acc[e] = make_float4(0.f, 0.f, 0.f, 0.f);
  float den = 0.f;

#pragma unroll 4
  for (int d4 = 0; d4 < 16; ++d4) {
    const float4 qv = *(const float4*)(qrow + 4 * d4);
    const float qd[4] = {fmaxf(qv.x, 0.f) + kEps, fmaxf(qv.y, 0.f) + kEps,
                         fmaxf(qv.z, 0.f) + kEps, fmaxf(qv.w, 0.f) + kEps};
#pragma unroll
    for (int dd = 0; dd < 4; ++dd) {
      const int d = 4 * d4 + dd;
      den = fmaf(qd[dd], Rb[KVSZ + d], den);
      const float* kvr = Rb + d * 64;          // uniform row -> SGPR broadcast
#pragma unroll
      for (int e = 0; e < 16; ++e) {
        acc[e].x = fmaf(qd[dd], kvr[4 * e + 0], acc[e].x);
        acc[e].y = fmaf(qd[dd], kvr[4 * e + 1], acc[e].y);
        acc[e].z = fmaf(qd[dd], kvr[4 * e + 2], acc[e].z);
        acc[e].w = fmaf(qd[dd], kvr[4 * e + 3], acc[e].w);
      }
    }
  }

  const float inv = 1.0f / den;
#pragma unroll
  for (int e = 0; e < 16; ++e) {
    acc[e].x *= inv; acc[e].y *= inv; acc[e].z *= inv; acc[e].w *= inv;
  }

  // staged coalesced store: batch bb covers 64 rows written by wave bb
  float* ob = out + ((size_t)bh * kS + (size_t)rowblk * 256) * kD;
  const int wid = tid >> 6, l = tid & 63;
  for (int bb = 0; bb < 4; ++bb) {
    if (wid == bb) {
#pragma unroll
      for (int e = 0; e < 16; ++e) *(float4*)&ost[l * 68 + 4 * e] = acc[e];
    }
    __syncthreads();
#pragma unroll
    for (int jj = 0; jj < 4; ++jj) {
      const int g = tid + 256 * jj;
      const int r = g >> 4, c = g & 15;
      *(float4*)&ob[(size_t)(bb * 64 + r) * kD + 4 * c] =
          *(const float4*)&ost[r * 68 + 4 * c];
    }
    __syncthreads();
  }
}

extern "C" void kernel_launch(void* const* d_in, const int* in_sizes, int n_in,
                              void* d_out, int out_size, void* d_ws, size_t ws_size,
                              hipStream_t stream) {
  const float* query = (const float*)d_in[0];
  const float* key   = (const float*)d_in[1];
  const float* value = (const float*)d_in[2];
  const float* mask  = (const float*)d_in[3];
  float* outp = (float*)d_out;

  // CH1 = S-chunks per bh; ONE segment per block. Pick largest that fits ws.
  auto need = [](int ch1) -> size_t {
    return (size_t)(kBH * ch1 + kBH) * SEG * sizeof(float);
  };
  int CH1 = 8;                                  // 9.2 MB, known-safe floor
  if (ws_size >= need(16)) CH1 = 16;            // 18.1 MB, 1024 blocks (4/CU)

  float* P = (float*)d_ws;                      // kBH*CH1 segments
  float* R = P + (size_t)kBH * CH1 * SEG;       // kBH segments (natural layout)

  hipLaunchKernelGGL(pa_kv_partial, dim3(kBH * CH1), dim3(256), 0, stream,
                     key, value, mask, P, CH1);
  hipLaunchKernelGGL(pa_reduce, dim3((kBH * F4PS + 255) / 256), dim3(256), 0, stream,
                     P, R, CH1);
  hipLaunchKernelGGL(pa_out, dim3(kBH * 16), dim3(256), 0, stream,
                     query, R, outp);
}

// Round 6
// 252.303 us; speedup vs baseline: 1.1544x; 1.0205x over previous
//
#include <hip/hip_runtime.h>

// PerformerAttention: B=4 H=16 S=4096 D=64, fp32.
//   q = relu(Q)+eps; k = (relu(K)+eps)*mask
//   kv[bh][d][e] = sum_s k[s][d]*v[s][e];  ksum[bh][d] = sum_s k[s][d]
//   out[s][e] = (sum_d q[s][d]*kv[d][e]) / (sum_d q[s][d]*ksum[d])
//
// R10: R9 proved depth-2 pipelining helps per-wave (VALU/wave +21%) but its
// +32 staging VGPRs (140) dropped occupancy 4->3 blocks/CU and cancelled the
// gain. This round: pipelining at ZERO extra registers. R4 single staging
// set (112 VGPR, (256,2), 4 blocks/CU) + mask-in-LDS + reordered round:
//   [kt compute (vmcnt(2), vq in flight) -> K write -> issue next kq]
//   fence
//   [V write (vmcnt(2), next-kq in flight) -> issue next vq]
//   fence
//   [FMA block (~1450 cyc) with next kq+vq in flight throughout]
// All waits are counted vmcnt(2) with ~a full round of slack; no A/B sets,
// no builtins. Empty asm "memory" fences pin the issue points only.
// If the VGPR128/SGPR112 spill signature returns, fences alone trigger it
// (R5/R7/R8 had fences + global_load_lds; R9 clean with neither).
// pa_reduce / pa_out / launcher unchanged (attribution).

namespace {
constexpr int kB = 4, kH = 16, kS = 4096, kD = 64;
constexpr int kBH = kB * kH;
constexpr float kEps = 0.001f;

constexpr int KVSZ = kD * kD;     // 4096 floats
constexpr int SEG  = KVSZ + kD;   // 4160 floats per partial segment (kv + ksum)
constexpr int F4PS = SEG / 4;     // 1040 float4 per segment
}

// ---------------- Pass 1: partial kv + ksum, one segment per BLOCK ---------
__global__ __launch_bounds__(256, 2)   // (256,4) caused a 64-VGPR spill disaster; do not re-add
void pa_kv_partial(const float* __restrict__ key, const float* __restrict__ value,
                   const float* __restrict__ mask, float* __restrict__ P, int ch1) {
  __shared__ float smem[4096];   // 4 waves x (ks 512 + vs 512); reused for combine
  __shared__ float msk[512];     // block's mask slice (LDS, not per-round VMEM)
  __shared__ float ksm[256];     // per-wave ksum staging

  const int tid  = threadIdx.x;
  const int wid  = tid >> 6;
  const int lane = tid & 63;

  const int bh    = blockIdx.x / ch1;
  const int chunk = blockIdx.x - bh * ch1;
  const int b     = bh >> 4;                 // kH = 16
  const int rows  = kS / ch1;
  const int s0    = chunk * rows;
  const int tiles = rows >> 5;               // 8-row tiles, strided by 4 waves

  const float* kb = key   + (size_t)bh * kS * kD;
  const float* vb = value + (size_t)bh * kS * kD;
  const float* mb = mask  + (size_t)b * kS;

  for (int i = tid; i < rows; i += 256) msk[i] = mb[s0 + i];
  __syncthreads();

  float* ksT = smem + wid * 1024;            // 8 x 64 (wave-private)
  float* vsT = smem + wid * 1024 + 512;      // 8 x 64

  const int lrow = lane >> 4;                // 0..3   (load map)
  const int lcol = (lane & 15) << 2;         // 0..60
  const int ti   = lane >> 3;                // 0..7   (compute map: d rows 8*ti..)
  const int tj   = lane & 7;                 // 0..7   (e cols 8*tj..)

  float acc[8][8];
#pragma unroll
  for (int i = 0; i < 8; ++i)
#pragma unroll
    for (int j = 0; j < 8; ++j) acc[i][j] = 0.f;
  float4 ksacc = make_float4(0.f, 0.f, 0.f, 0.f);

  // Per-lane element offsets within a tile (tile base row = s0 + t*32 + wid*8)
  const size_t eoff0 = (size_t)(lrow)     * kD + lcol;   // rows 0..3 of tile
  const size_t eoff1 = (size_t)(lrow + 4) * kD + lcol;   // rows 4..7 of tile
  const int    trow  = wid * 8;                          // wave row in 32-row group

  // ---- prologue: tile 0 into the single staging set (issue order k,k,v,v) --
  {
    const float* kt0p = kb + (size_t)(s0 + trow) * kD;
    const float* vt0p = vb + (size_t)(s0 + trow) * kD;
    // declared below; assigned here via lambda-free straight code
  }
  float4 kq0, kq1, vq0, vq1;
  {
    const float* kt0p = kb + (size_t)(s0 + trow) * kD;
    const float* vt0p = vb + (size_t)(s0 + trow) * kD;
    kq0 = *(const float4*)(kt0p + eoff0);
    kq1 = *(const float4*)(kt0p + eoff1);
    vq0 = *(const float4*)(vt0p + eoff0);
    vq1 = *(const float4*)(vt0p + eoff1);
  }

  for (int t = 0; t < tiles; ++t) {
    const int rb = t * 32 + trow;
    const float m0 = msk[rb + lrow];
    const float m1 = msk[rb + 4 + lrow];

    // --- region 1: K process (waits vmcnt(2); vq still in flight),
    //     K tile write, then ISSUE next-tile K loads ---
    float4 kt0, kt1;
    kt0.x = (fmaxf(kq0.x, 0.f) + kEps) * m0;
    kt0.y = (fmaxf(kq0.y, 0.f) + kEps) * m0;
    kt0.z = (fmaxf(kq0.z, 0.f) + kEps) * m0;
    kt0.w = (fmaxf(kq0.w, 0.f) + kEps) * m0;
    kt1.x = (fmaxf(kq1.x, 0.f) + kEps) * m1;
    kt1.y = (fmaxf(kq1.y, 0.f) + kEps) * m1;
    kt1.z = (fmaxf(kq1.z, 0.f) + kEps) * m1;
    kt1.w = (fmaxf(kq1.w, 0.f) + kEps) * m1;

    ksacc.x += kt0.x + kt1.x;
    ksacc.y += kt0.y + kt1.y;
    ksacc.z += kt0.z + kt1.z;
    ksacc.w += kt0.w + kt1.w;

    *(float4*)&ksT[lrow * 64 + lcol]       = kt0;
    *(float4*)&ksT[(lrow + 4) * 64 + lcol] = kt1;

    if (t + 1 < tiles) {
      const float* kn = kb + (size_t)(s0 + (t + 1) * 32 + trow) * kD;
      kq0 = *(const float4*)(kn + eoff0);
      kq1 = *(const float4*)(kn + eoff1);
    }
    asm volatile("" ::: "memory");   // pin: next-K issued before V writes

    // --- region 2: V tile write (waits vmcnt(2); next-K stays in flight),
    //     then ISSUE next-tile V loads ---
    *(float4*)&vsT[lrow * 64 + lcol]       = vq0;
    *(float4*)&vsT[(lrow + 4) * 64 + lcol] = vq1;

    if (t + 1 < tiles) {
      const float* vn = vb + (size_t)(s0 + (t + 1) * 32 + trow) * kD;
      vq0 = *(const float4*)(vn + eoff0);
      vq1 = *(const float4*)(vn + eoff1);
    }
    asm volatile("" ::: "memory");   // pin: next-V issued before FMA block

    // --- region 3: FMA block; next kq+vq in flight the whole time.
    //     Same-wave DS is in-order: reads see this round's writes. ---
#pragma unroll
    for (int ss = 0; ss < 8; ++ss) {
      const float4 kf0 = *(const float4*)&ksT[ss * 64 + 8 * ti];
      const float4 kf1 = *(const float4*)&ksT[ss * 64 + 8 * ti + 4];
      const float4 vf0 = *(const float4*)&vsT[ss * 64 + 8 * tj];
      const float4 vf1 = *(const float4*)&vsT[ss * 64 + 8 * tj + 4];
      const float ka[8] = {kf0.x, kf0.y, kf0.z, kf0.w, kf1.x, kf1.y, kf1.z, kf1.w};
      const float va[8] = {vf0.x, vf0.y, vf0.z, vf0.w, vf1.x, vf1.y, vf1.z, vf1.w};
#pragma unroll
      for (int i = 0; i < 8; ++i)
#pragma unroll
        for (int j = 0; j < 8; ++j) acc[i][j] = fmaf(ka[i], va[j], acc[i][j]);
    }
  }

  // per-wave ksum fold: lanes sharing (lane&15) hold disjoint row partials
  ksacc.x += __shfl_xor(ksacc.x, 16); ksacc.x += __shfl_xor(ksacc.x, 32);
  ksacc.y += __shfl_xor(ksacc.y, 16); ksacc.y += __shfl_xor(ksacc.y, 32);
  ksacc.z += __shfl_xor(ksacc.z, 16); ksacc.z += __shfl_xor(ksacc.z, 32);
  ksacc.w += __shfl_xor(ksacc.w, 16); ksacc.w += __shfl_xor(ksacc.w, 32);
  if (lane < 16) *(float4*)&ksm[wid * 64 + 4 * lane] = ksacc;

  // block combine: wave w adds its 8x8 acc into smem[4096] (permuted layout:
  // f4 slot j*64+lane = kv[8*(lane>>3)+(j>>1)][8*(lane&7)+4*(j&1)..])
#pragma unroll
  for (int w = 0; w < 4; ++w) {
    __syncthreads();
    if (wid == w) {
#pragma unroll
      for (int i = 0; i < 8; ++i)
#pragma unroll
        for (int jj = 0; jj < 2; ++jj) {
          const int j = i * 2 + jj;
          float4 o = make_float4(acc[i][jj * 4 + 0], acc[i][jj * 4 + 1],
                                 acc[i][jj * 4 + 2], acc[i][jj * 4 + 3]);
          float* p = &smem[(size_t)(j * 64 + lane) * 4];
          if (w != 0) {
            const float4 prev = *(const float4*)p;
            o.x += prev.x; o.y += prev.y; o.z += prev.z; o.w += prev.w;
          }
          *(float4*)p = o;
        }
    }
  }
  __syncthreads();

  // cooperative coalesced store of the single block segment
  float* Pd = P + (size_t)blockIdx.x * SEG;
#pragma unroll
  for (int i = 0; i < 4; ++i) {
    const int idx = tid + 256 * i;
    *(float4*)&Pd[(size_t)idx * 4] = *(const float4*)&smem[(size_t)idx * 4];
  }
  if (tid < kD)
    Pd[KVSZ + tid] = ksm[tid] + ksm[64 + tid] + ksm[128 + tid] + ksm[192 + tid];
}

// ---------------- Reduce: sum block partials, un-permute kv ----------------
__global__ __launch_bounds__(256)
void pa_reduce(const float* __restrict__ P, float* __restrict__ R, int nseg) {
  const int gid = blockIdx.x * 256 + threadIdx.x;
  if (gid >= kBH * F4PS) return;
  const int bh  = gid / F4PS;
  const int pos = gid - bh * F4PS;

  const float* base = P + (size_t)bh * nseg * SEG + (size_t)pos * 4;
  float ax = 0.f, ay = 0.f, az = 0.f, aw = 0.f;
  for (int c = 0; c < nseg; ++c) {
    const float4 t = *(const float4*)(base + (size_t)c * SEG);
    ax += t.x; ay += t.y; az += t.z; aw += t.w;
  }

  int dpos;
  if (pos < KVSZ / 4) {          // un-permute to natural [d][e]
    const int j  = pos >> 6, ln = pos & 63;
    const int d  = 8 * (ln >> 3) + (j >> 1);
    const int e4 = 2 * (ln & 7) + (j & 1);
    dpos = d * 16 + e4;
  } else {
    dpos = pos;                  // ksum already natural
  }
  *(float4*)&R[(size_t)bh * SEG + (size_t)dpos * 4] = make_float4(ax, ay, az, aw);
}

// ---------------- Pass 2: out = (q . kv) / (q . ksum) ----------------------
__global__ __launch_bounds__(256)
void pa_out(const float* __restrict__ query, const float* __restrict__ R,
            float* __restrict__ out) {
  __shared__ float ost[64 * 68];   // 64-row output staging, pad 68 (17 KiB)

  const int tid    = threadIdx.x;
  const int bh     = blockIdx.x >> 4;
  const int rowblk = blockIdx.x & 15;
  const int s      = rowblk * 256 + tid;

  const float* qrow = query + ((size_t)bh * kS + s) * kD;
  const float* Rb   = R + (size_t)bh * SEG;   // wave-uniform -> scalar loads

  float4 acc[16];
#pragma unroll
  for (int e = 0; e < 16; ++e) acc[e] = make_float4(0.f, 0.f, 0.f, 0.f);
  float den = 0.f;

#pragma unroll 4
  for (int d4 = 0; d4 < 16; ++d4) {
    const float4 qv = *(const float4*)(qrow + 4 * d4);
    const float qd[4] = {fmaxf(qv.x, 0.f) + kEps, fmaxf(qv.y, 0.f) + kEps,
                         fmaxf(qv.z, 0.f) + kEps, fmaxf(qv.w, 0.f) + kEps};
#pragma unroll
    for (int dd = 0; dd < 4; ++dd) {
      const int d = 4 * d4 + dd;
      den = fmaf(qd[dd], Rb[KVSZ + d], den);
      const float* kvr = Rb + d * 64;          // uniform row -> SGPR broadcast
#pragma unroll
      for (int e = 0; e < 16; ++e) {
        acc[e].x = fmaf(qd[dd], kvr[4 * e + 0], acc[e].x);
        acc[e].y = fmaf(qd[dd], kvr[4 * e + 1], acc[e].y);
        acc[e].z = fmaf(qd[dd], kvr[4 * e + 2], acc[e].z);
        acc[e].w = fmaf(qd[dd], kvr[4 * e + 3], acc[e].w);
      }
    }
  }

  const float inv = 1.0f / den;
#pragma unroll
  for (int e = 0; e < 16; ++e) {
    acc[e].x *= inv; acc[e].y *= inv; acc[e].z *= inv; acc[e].w *= inv;
  }

  // staged coalesced store: batch bb covers 64 rows written by wave bb
  float* ob = out + ((size_t)bh * kS + (size_t)rowblk * 256) * kD;
  const int wid = tid >> 6, l = tid & 63;
  for (int bb = 0; bb < 4; ++bb) {
    if (wid == bb) {
#pragma unroll
      for (int e = 0; e < 16; ++e) *(float4*)&ost[l * 68 + 4 * e] = acc[e];
    }
    __syncthreads();
#pragma unroll
    for (int jj = 0; jj < 4; ++jj) {
      const int g = tid + 256 * jj;
      const int r = g >> 4, c = g & 15;
      *(float4*)&ob[(size_t)(bb * 64 + r) * kD + 4 * c] =
          *(const float4*)&ost[r * 68 + 4 * c];
    }
    __syncthreads();
  }
}

extern "C" void kernel_launch(void* const* d_in, const int* in_sizes, int n_in,
                              void* d_out, int out_size, void* d_ws, size_t ws_size,
                              hipStream_t stream) {
  const float* query = (const float*)d_in[0];
  const float* key   = (const float*)d_in[1];
  const float* value = (const float*)d_in[2];
  const float* mask  = (const float*)d_in[3];
  float* outp = (float*)d_out;

  // CH1 = S-chunks per bh; ONE segment per block. Pick largest that fits ws.
  auto need = [](int ch1) -> size_t {
    return (size_t)(kBH * ch1 + kBH) * SEG * sizeof(float);
  };
  int CH1 = 8;                                  // 9.2 MB, known-safe floor
  if (ws_size >= need(16)) CH1 = 16;            // 18.1 MB, 1024 blocks (4/CU)

  float* P = (float*)d_ws;                      // kBH*CH1 segments
  float* R = P + (size_t)kBH * CH1 * SEG;       // kBH segments (natural layout)

  hipLaunchKernelGGL(pa_kv_partial, dim3(kBH * CH1), dim3(256), 0, stream,
                     key, value, mask, P, CH1);
  hipLaunchKernelGGL(pa_reduce, dim3((kBH * F4PS + 255) / 256), dim3(256), 0, stream,
                     P, R, CH1);
  hipLaunchKernelGGL(pa_out, dim3(kBH * 16), dim3(256), 0, stream,
                     query, R, outp);
}